// Round 1
// baseline (956.691 us; speedup 1.0000x reference)
//
#include <hip/hip_runtime.h>

#define N_NODES 100000
#define N_EDGES 1200000
#define D 64           // NDIM_IN = EDIMS = NDIM_OUT = 64

// ---------------------------------------------------------------------------
// Stage 1: edge aggregation (linearity trick: aggregate inputs, matmul later)
//   agg_h[d] += nfeats[src[e]];  agg_e[d] += efeats[e];  deg[d] += 1
// One wave (64 lanes) per edge; lane = feature dim.
// ---------------------------------------------------------------------------
__global__ __launch_bounds__(256) void edge_agg_kernel(
    const float* __restrict__ nfeats, const float* __restrict__ efeats,
    const int* __restrict__ src, const int* __restrict__ dst,
    float* __restrict__ agg_h,   // = d_out, zeroed
    float* __restrict__ agg_e,   // in ws, zeroed
    float* __restrict__ deg)     // in ws, zeroed
{
    int wave = (int)((blockIdx.x * blockDim.x + threadIdx.x) >> 6);
    int lane = threadIdx.x & 63;
    if (wave >= N_EDGES) return;
    int s = src[wave];
    int d = dst[wave];
    float hv = nfeats[(size_t)s * D + lane];
    float ev = efeats[(size_t)wave * D + lane];
    atomicAdd(&agg_h[(size_t)d * D + lane], hv);
    atomicAdd(&agg_e[(size_t)d * D + lane], ev);
    if (lane == 0) atomicAdd(&deg[d], 1.0f);
}

// ---------------------------------------------------------------------------
// Stage 2: node update.
//   msum = agg_h @ Wm[0:64] + agg_e @ Wm[64:128] + deg * b_msg
//   h_neigh = deg > 0 ? msum / deg : 0
//   h = relu(nfeats @ Wa[0:64] + h_neigh @ Wa[64:128] + b_apply)
// One wave per node, lane j computes output dim j. Weights staged in LDS
// (64 KB); row broadcast via __shfl (wave64).
// ---------------------------------------------------------------------------
__global__ __launch_bounds__(256) void node_update_kernel(
    const float* __restrict__ nfeats,
    const float* __restrict__ W_msg, const float* __restrict__ b_msg,
    const float* __restrict__ W_apply, const float* __restrict__ b_apply,
    const float* __restrict__ agg_e, const float* __restrict__ deg,
    float* __restrict__ out)   // holds agg_h on entry, final h on exit
{
    __shared__ float sWm[128 * 64];
    __shared__ float sWa[128 * 64];
    int tid = threadIdx.x;
    #pragma unroll
    for (int i = 0; i < 32; ++i) {          // 128*64/256 = 32 per thread
        sWm[i * 256 + tid] = W_msg[i * 256 + tid];
        sWa[i * 256 + tid] = W_apply[i * 256 + tid];
    }
    __syncthreads();

    int lane = tid & 63;
    int wid  = tid >> 6;
    int node = blockIdx.x * 4 + wid;
    if (node >= N_NODES) return;

    float ah = out[(size_t)node * D + lane];     // agg_h row
    float ae = agg_e[(size_t)node * D + lane];
    float dg = deg[node];

    // msum_j
    float msum = dg * b_msg[lane];
    #pragma unroll
    for (int k = 0; k < 64; ++k) {
        msum += __shfl(ah, k) * sWm[k * 64 + lane];
        msum += __shfl(ae, k) * sWm[(64 + k) * 64 + lane];
    }
    float hn = (dg > 0.0f) ? (msum / dg) : 0.0f;

    float nf = nfeats[(size_t)node * D + lane];
    float acc = b_apply[lane];
    #pragma unroll
    for (int k = 0; k < 64; ++k) {
        acc += __shfl(nf, k) * sWa[k * 64 + lane];
        acc += __shfl(hn, k) * sWa[(64 + k) * 64 + lane];
    }
    out[(size_t)node * D + lane] = fmaxf(acc, 0.0f);
}

extern "C" void kernel_launch(void* const* d_in, const int* in_sizes, int n_in,
                              void* d_out, int out_size, void* d_ws, size_t ws_size,
                              hipStream_t stream) {
    const float* nfeats  = (const float*)d_in[0];
    const float* efeats  = (const float*)d_in[1];
    const int*   src     = (const int*)d_in[2];
    const int*   dst     = (const int*)d_in[3];
    const float* W_msg   = (const float*)d_in[4];
    const float* b_msg   = (const float*)d_in[5];
    const float* W_apply = (const float*)d_in[6];
    const float* b_apply = (const float*)d_in[7];

    float* out   = (float*)d_out;                    // doubles as agg_h
    float* agg_e = (float*)d_ws;                     // 25.6 MB
    float* deg   = agg_e + (size_t)N_NODES * D;      // 0.4 MB

    hipMemsetAsync(d_out, 0, (size_t)N_NODES * D * sizeof(float), stream);
    hipMemsetAsync(d_ws, 0, ((size_t)N_NODES * D + N_NODES) * sizeof(float), stream);

    // one wave per edge
    long long threads = (long long)N_EDGES * 64;
    int blocks = (int)((threads + 255) / 256);
    edge_agg_kernel<<<blocks, 256, 0, stream>>>(nfeats, efeats, src, dst,
                                                out, agg_e, deg);

    node_update_kernel<<<(N_NODES + 3) / 4, 256, 0, stream>>>(
        nfeats, W_msg, b_msg, W_apply, b_apply, agg_e, deg, out);
}

// Round 2
// 583.568 us; speedup vs baseline: 1.6394x; 1.6394x over previous
//
#include <hip/hip_runtime.h>

#define N_NODES 100000
#define N_EDGES 1200000
#define D 64

// ---------------- CSR build ----------------
__global__ __launch_bounds__(256) void count_deg_kernel(
    const int* __restrict__ dst, int* __restrict__ deg)
{
    int e = blockIdx.x * 256 + threadIdx.x;
    if (e < N_EDGES) atomicAdd(&deg[dst[e]], 1);
}

// block scans 1024 elements (256 thr x 4), writes exclusive prefix + block sum
__global__ __launch_bounds__(256) void scan_block_kernel(
    const int* __restrict__ deg, int* __restrict__ offs, int* __restrict__ blocksums)
{
    __shared__ int s[256];
    int tid = threadIdx.x;
    int base = blockIdx.x * 1024;
    int v[4]; int sum = 0;
    #pragma unroll
    for (int j = 0; j < 4; ++j) {
        int idx = base + tid * 4 + j;
        v[j] = (idx < N_NODES) ? deg[idx] : 0;
        sum += v[j];
    }
    s[tid] = sum; __syncthreads();
    for (int off = 1; off < 256; off <<= 1) {
        int t = (tid >= off) ? s[tid - off] : 0;
        __syncthreads();
        s[tid] += t;
        __syncthreads();
    }
    int run = s[tid] - sum;                     // exclusive prefix of thread sums
    #pragma unroll
    for (int j = 0; j < 4; ++j) {
        int idx = base + tid * 4 + j;
        if (idx < N_NODES) offs[idx] = run;
        run += v[j];
    }
    if (tid == 255) blocksums[blockIdx.x] = s[255];
}

__global__ void scan_tops_kernel(int* __restrict__ blocksums, int nb)
{
    __shared__ int s[128];
    int tid = threadIdx.x;
    int v = (tid < nb) ? blocksums[tid] : 0;
    s[tid] = v; __syncthreads();
    for (int off = 1; off < 128; off <<= 1) {
        int t = (tid >= off) ? s[tid - off] : 0;
        __syncthreads();
        s[tid] += t;
        __syncthreads();
    }
    if (tid < nb) blocksums[tid] = s[tid] - v;  // exclusive
}

__global__ __launch_bounds__(256) void add_tops_kernel(
    int* __restrict__ offs, const int* __restrict__ blocksums)
{
    int i = blockIdx.x * 256 + threadIdx.x;
    if (i < N_NODES) offs[i] += blocksums[i >> 10];
}

__global__ __launch_bounds__(256) void scatter_edges_kernel(
    const int* __restrict__ src, const int* __restrict__ dst,
    const int* __restrict__ offs, int* __restrict__ cursor,
    int* __restrict__ eid_s, int* __restrict__ src_s)
{
    int e = blockIdx.x * 256 + threadIdx.x;
    if (e >= N_EDGES) return;
    int d = dst[e];
    int pos = offs[d] + atomicAdd(&cursor[d], 1);
    eid_s[pos] = e;
    src_s[pos] = src[e];
}

// ---------------- fused gather + node update ----------------
// 1024 threads = 16 waves; one wave per node; lane = feature dim.
// LDS: both weight matrices (64 KB) -> 2 blocks/CU = 32 waves/CU.
__global__ __launch_bounds__(1024) void fused_agg_update_kernel(
    const float* __restrict__ nfeats, const float* __restrict__ efeats,
    const float* __restrict__ W_msg, const float* __restrict__ b_msg,
    const float* __restrict__ W_apply, const float* __restrict__ b_apply,
    const int* __restrict__ offs, const int* __restrict__ deg_i,
    const int* __restrict__ eid_s, const int* __restrict__ src_s,
    float* __restrict__ out)
{
    __shared__ float sWm[128 * 64];
    __shared__ float sWa[128 * 64];
    int tid = threadIdx.x;
    #pragma unroll
    for (int i = 0; i < 8; ++i) {               // 8192/1024 = 8 per thread
        sWm[i * 1024 + tid] = W_msg[i * 1024 + tid];
        sWa[i * 1024 + tid] = W_apply[i * 1024 + tid];
    }
    __syncthreads();

    int lane = tid & 63;
    int wid  = tid >> 6;
    int node = blockIdx.x * 16 + wid;
    if (node >= N_NODES) return;

    int beg = offs[node];
    int dgi = deg_i[node];

    float sh = 0.0f, se = 0.0f;
    for (int i = 0; i < dgi; ++i) {
        int e = eid_s[beg + i];
        int s = src_s[beg + i];
        se += efeats[(size_t)e * D + lane];
        sh += nfeats[(size_t)s * D + lane];
    }

    float dg = (float)dgi;
    float msum = dg * b_msg[lane];
    #pragma unroll
    for (int k = 0; k < 64; ++k) {
        msum += __shfl(sh, k) * sWm[k * 64 + lane];
        msum += __shfl(se, k) * sWm[(64 + k) * 64 + lane];
    }
    float hn = (dgi > 0) ? (msum / dg) : 0.0f;

    float nf = nfeats[(size_t)node * D + lane];
    float acc = b_apply[lane];
    #pragma unroll
    for (int k = 0; k < 64; ++k) {
        acc += __shfl(nf, k) * sWa[k * 64 + lane];
        acc += __shfl(hn, k) * sWa[(64 + k) * 64 + lane];
    }
    out[(size_t)node * D + lane] = fmaxf(acc, 0.0f);
}

extern "C" void kernel_launch(void* const* d_in, const int* in_sizes, int n_in,
                              void* d_out, int out_size, void* d_ws, size_t ws_size,
                              hipStream_t stream) {
    const float* nfeats  = (const float*)d_in[0];
    const float* efeats  = (const float*)d_in[1];
    const int*   src     = (const int*)d_in[2];
    const int*   dst     = (const int*)d_in[3];
    const float* W_msg   = (const float*)d_in[4];
    const float* b_msg   = (const float*)d_in[5];
    const float* W_apply = (const float*)d_in[6];
    const float* b_apply = (const float*)d_in[7];
    float* out = (float*)d_out;

    // workspace layout (ints): [deg | cursor | offs | blocksums(128) | eid_s | src_s]
    int* deg_i     = (int*)d_ws;
    int* cursor    = deg_i + N_NODES;
    int* offs      = cursor + N_NODES;
    int* blocksums = offs + N_NODES;
    int* eid_s     = blocksums + 128;
    int* src_s     = eid_s + N_EDGES;

    // zero deg + cursor (contiguous)
    hipMemsetAsync(d_ws, 0, (size_t)2 * N_NODES * sizeof(int), stream);

    int eb = (N_EDGES + 255) / 256;
    count_deg_kernel<<<eb, 256, 0, stream>>>(dst, deg_i);

    int nscan = (N_NODES + 1023) / 1024;   // 98
    scan_block_kernel<<<nscan, 256, 0, stream>>>(deg_i, offs, blocksums);
    scan_tops_kernel<<<1, 128, 0, stream>>>(blocksums, nscan);
    add_tops_kernel<<<(N_NODES + 255) / 256, 256, 0, stream>>>(offs, blocksums);

    scatter_edges_kernel<<<eb, 256, 0, stream>>>(src, dst, offs, cursor, eid_s, src_s);

    fused_agg_update_kernel<<<(N_NODES + 15) / 16, 1024, 0, stream>>>(
        nfeats, efeats, W_msg, b_msg, W_apply, b_apply,
        offs, deg_i, eid_s, src_s, out);
}

// Round 3
// 303.851 us; speedup vs baseline: 3.1486x; 1.9206x over previous
//
#include <hip/hip_runtime.h>

#define N_NODES 100000
#define N_EDGES 1200000
#define D 64

// ---------------- CSR build ----------------
__global__ __launch_bounds__(256) void count_deg_kernel(
    const int* __restrict__ dst, int* __restrict__ deg)
{
    int e = blockIdx.x * 256 + threadIdx.x;
    if (e < N_EDGES) atomicAdd(&deg[dst[e]], 1);
}

__global__ __launch_bounds__(256) void scan_block_kernel(
    const int* __restrict__ deg, int* __restrict__ offs, int* __restrict__ blocksums)
{
    __shared__ int s[256];
    int tid = threadIdx.x;
    int base = blockIdx.x * 1024;
    int v[4]; int sum = 0;
    #pragma unroll
    for (int j = 0; j < 4; ++j) {
        int idx = base + tid * 4 + j;
        v[j] = (idx < N_NODES) ? deg[idx] : 0;
        sum += v[j];
    }
    s[tid] = sum; __syncthreads();
    for (int off = 1; off < 256; off <<= 1) {
        int t = (tid >= off) ? s[tid - off] : 0;
        __syncthreads();
        s[tid] += t;
        __syncthreads();
    }
    int run = s[tid] - sum;
    #pragma unroll
    for (int j = 0; j < 4; ++j) {
        int idx = base + tid * 4 + j;
        if (idx < N_NODES) offs[idx] = run;
        run += v[j];
    }
    if (tid == 255) blocksums[blockIdx.x] = s[255];
}

__global__ void scan_tops_kernel(int* __restrict__ blocksums, int nb)
{
    __shared__ int s[128];
    int tid = threadIdx.x;
    int v = (tid < nb) ? blocksums[tid] : 0;
    s[tid] = v; __syncthreads();
    for (int off = 1; off < 128; off <<= 1) {
        int t = (tid >= off) ? s[tid - off] : 0;
        __syncthreads();
        s[tid] += t;
        __syncthreads();
    }
    if (tid < nb) blocksums[tid] = s[tid] - v;
}

__global__ __launch_bounds__(256) void add_tops_kernel(
    int* __restrict__ offs, const int* __restrict__ blocksums)
{
    int i = blockIdx.x * 256 + threadIdx.x;
    if (i < N_NODES) offs[i] += blocksums[i >> 10];
}

__global__ __launch_bounds__(256) void scatter_edges_kernel(
    const int* __restrict__ src, const int* __restrict__ dst,
    const int* __restrict__ offs, int* __restrict__ cursor,
    int2* __restrict__ idx_s)
{
    int e = blockIdx.x * 256 + threadIdx.x;
    if (e >= N_EDGES) return;
    int d = dst[e];
    int pos = offs[d] + atomicAdd(&cursor[d], 1);
    idx_s[pos] = make_int2(e, src[e]);
}

// ---------------- weight prep: Wf = W_msg @ Wa_bot, c1 = b_msg @ Wa_bot ----
__global__ __launch_bounds__(64) void prep_w_kernel(
    const float* __restrict__ W_msg, const float* __restrict__ b_msg,
    const float* __restrict__ W_apply, float* __restrict__ Wf, float* __restrict__ c1)
{
    int j = threadIdx.x;
    int i = blockIdx.x;
    float acc = 0.f;
    if (i < 128) {
        for (int k = 0; k < 64; ++k)
            acc = fmaf(W_msg[i * 64 + k], W_apply[(64 + k) * 64 + j], acc);
        Wf[i * 64 + j] = acc;
    } else {
        for (int k = 0; k < 64; ++k)
            acc = fmaf(b_msg[k], W_apply[(64 + k) * 64 + j], acc);
        c1[j] = acc;
    }
}

// ---------------- gather: one wave per node, unroll x4, scalarized indices --
__global__ __launch_bounds__(256) void gather_kernel(
    const float* __restrict__ nfeats, const float* __restrict__ efeats,
    const int2* __restrict__ idx_s, const int* __restrict__ offs,
    const int* __restrict__ deg, float* __restrict__ agg_h, float* __restrict__ agg_e)
{
    int w = (int)((blockIdx.x * blockDim.x + threadIdx.x) >> 6);
    int lane = threadIdx.x & 63;
    if (w >= N_NODES) return;
    int beg = __builtin_amdgcn_readfirstlane(offs[w]);
    int dgi = __builtin_amdgcn_readfirstlane(deg[w]);
    float sh = 0.f, se = 0.f;
    int i = 0;
    for (; i + 4 <= dgi; i += 4) {
        int2 p0 = idx_s[beg + i + 0];
        int2 p1 = idx_s[beg + i + 1];
        int2 p2 = idx_s[beg + i + 2];
        int2 p3 = idx_s[beg + i + 3];
        float a0 = efeats[(size_t)p0.x * D + lane];
        float a1 = efeats[(size_t)p1.x * D + lane];
        float a2 = efeats[(size_t)p2.x * D + lane];
        float a3 = efeats[(size_t)p3.x * D + lane];
        float b0 = nfeats[(size_t)p0.y * D + lane];
        float b1 = nfeats[(size_t)p1.y * D + lane];
        float b2 = nfeats[(size_t)p2.y * D + lane];
        float b3 = nfeats[(size_t)p3.y * D + lane];
        se += (a0 + a1) + (a2 + a3);
        sh += (b0 + b1) + (b2 + b3);
    }
    for (; i < dgi; ++i) {
        int2 p = idx_s[beg + i];
        se += efeats[(size_t)p.x * D + lane];
        sh += nfeats[(size_t)p.y * D + lane];
    }
    agg_h[(size_t)w * D + lane] = sh;
    agg_e[(size_t)w * D + lane] = se;
}

// ---------------- node update: lane = node, weights via scalar regs ---------
// acc = nf@Wa_top + s*([sh|se]@Wf);  out = relu(acc + gate*c1 + b_apply)
__global__ __launch_bounds__(64) void node_update_kernel(
    const float* __restrict__ nfeats, const float* __restrict__ W_apply,
    const float* __restrict__ b_apply, const float* __restrict__ Wf,
    const float* __restrict__ c1, const float* __restrict__ agg_e,
    const int* __restrict__ deg, float* __restrict__ out /* holds agg_h */)
{
    __shared__ float sT[64 * 65];
    int lane = threadIdx.x;
    int node0 = blockIdx.x * 64 + lane;
    int node = node0 < N_NODES ? node0 : N_NODES - 1;
    int dgi = deg[node];
    float s = dgi > 0 ? 1.f / (float)dgi : 0.f;
    float gate = dgi > 0 ? 1.f : 0.f;

    float acc[64];
    #pragma unroll
    for (int j = 0; j < 64; ++j) acc[j] = 0.f;

    const float* nfr = nfeats + (size_t)node * D;
    const float* shr = out + (size_t)node * D;      // agg_h
    const float* ser = agg_e + (size_t)node * D;

    // nf @ Wa_top (rows 0..63 of W_apply)
    for (int k4 = 0; k4 < 64; k4 += 4) {
        float4 x = *(const float4*)(nfr + k4);
        #pragma unroll
        for (int kk = 0; kk < 4; ++kk) {
            float xv = (&x.x)[kk];
            const float* wr = W_apply + (size_t)(k4 + kk) * 64;
            #pragma unroll
            for (int j = 0; j < 64; ++j) acc[j] = fmaf(xv, wr[j], acc[j]);
        }
    }
    // s*sh @ Wf rows 0..63
    for (int k4 = 0; k4 < 64; k4 += 4) {
        float4 x = *(const float4*)(shr + k4);
        #pragma unroll
        for (int kk = 0; kk < 4; ++kk) {
            float xv = (&x.x)[kk] * s;
            const float* wr = Wf + (size_t)(k4 + kk) * 64;
            #pragma unroll
            for (int j = 0; j < 64; ++j) acc[j] = fmaf(xv, wr[j], acc[j]);
        }
    }
    // s*se @ Wf rows 64..127
    for (int k4 = 0; k4 < 64; k4 += 4) {
        float4 x = *(const float4*)(ser + k4);
        #pragma unroll
        for (int kk = 0; kk < 4; ++kk) {
            float xv = (&x.x)[kk] * s;
            const float* wr = Wf + (size_t)(64 + k4 + kk) * 64;
            #pragma unroll
            for (int j = 0; j < 64; ++j) acc[j] = fmaf(xv, wr[j], acc[j]);
        }
    }

    #pragma unroll
    for (int j = 0; j < 64; ++j)
        sT[lane * 65 + j] = fmaxf(acc[j] + gate * c1[j] + b_apply[j], 0.f);
    __syncthreads();

    int nbase = blockIdx.x * 64;
    for (int n = 0; n < 64; ++n) {
        int nd = nbase + n;
        if (nd >= N_NODES) break;
        out[(size_t)nd * D + lane] = sT[n * 65 + lane];
    }
}

extern "C" void kernel_launch(void* const* d_in, const int* in_sizes, int n_in,
                              void* d_out, int out_size, void* d_ws, size_t ws_size,
                              hipStream_t stream) {
    const float* nfeats  = (const float*)d_in[0];
    const float* efeats  = (const float*)d_in[1];
    const int*   src     = (const int*)d_in[2];
    const int*   dst     = (const int*)d_in[3];
    const float* W_msg   = (const float*)d_in[4];
    const float* b_msg   = (const float*)d_in[5];
    const float* W_apply = (const float*)d_in[6];
    const float* b_apply = (const float*)d_in[7];
    float* out = (float*)d_out;

    // ws layout: [deg | cursor | offs | blocksums(128) | Wf(8192f) | c1(64f) | idx int2(E) | agg_e(N*64 f)]
    int* deg       = (int*)d_ws;
    int* cursor    = deg + N_NODES;
    int* offs      = cursor + N_NODES;
    int* blocksums = offs + N_NODES;
    float* Wf      = (float*)(blocksums + 128);
    float* c1      = Wf + 128 * 64;
    int2* idx_s    = (int2*)(c1 + 64);
    float* agg_e   = (float*)(idx_s + N_EDGES);

    hipMemsetAsync(d_ws, 0, (size_t)2 * N_NODES * sizeof(int), stream);

    prep_w_kernel<<<129, 64, 0, stream>>>(W_msg, b_msg, W_apply, Wf, c1);

    int eb = (N_EDGES + 255) / 256;
    count_deg_kernel<<<eb, 256, 0, stream>>>(dst, deg);

    int nscan = (N_NODES + 1023) / 1024;   // 98
    scan_block_kernel<<<nscan, 256, 0, stream>>>(deg, offs, blocksums);
    scan_tops_kernel<<<1, 128, 0, stream>>>(blocksums, nscan);
    add_tops_kernel<<<(N_NODES + 255) / 256, 256, 0, stream>>>(offs, blocksums);

    scatter_edges_kernel<<<eb, 256, 0, stream>>>(src, dst, offs, cursor, idx_s);

    gather_kernel<<<N_NODES / 4, 256, 0, stream>>>(
        nfeats, efeats, idx_s, offs, deg, out /*agg_h*/, agg_e);

    node_update_kernel<<<(N_NODES + 63) / 64, 64, 0, stream>>>(
        nfeats, W_apply, b_apply, Wf, c1, agg_e, deg, out);
}